// Round 4
// baseline (881.357 us; speedup 1.0000x reference)
//
#include <hip/hip_runtime.h>

// LSTM RNN_20263655702953 — MI355X (gfx950), round 8.
//
// Reference quirk: hs[:, -1, :] selects BATCH index 511 => single sequential
// LSTM chain (1024 steps, H=64), then (1024,64)@(64,2) projection.
//
// R8: SPILL-FREE single-wave recurrence. R7 proved the single-wave structure
// is issue-bound with NO mystery stall (88% SIMD busy) but spilled: w[4][64]
// = 256 VGPRs + working set > 256-reg arch cap -> VGPR_Count 148 + spill
// traffic (~790 VALU/step measured vs ~364 in source).
// R8 register budget:
//   - gates 0,1 (i,f) weights VGPR-resident: w0[64]+w1[64] = 128 VGPRs
//   - gates 2,3 (g,o) weights streamed from LDS每 step, TRANSPOSED layout
//     T[k4][lane] float4 (per-lane consecutive 16B -> conflict-free b128),
//     double-buffered 4-float4 batches (64 VGPRs in flight), prefetched one
//     FMA-batch (~160cy) ahead of use; addresses loop-invariant, independent
//     of h => latency fully covered. LDS stays OFF the serial h-path
//     (R5/R6 lesson).
//   - h broadcast: proven zero-latency readlane, 16-wide batches (R4 pattern,
//     sched_barrier(0) fences space the VALU->SGPR hazards).
// Total ~230 VGPRs < 256. Zero barriers / zero cross-wave ops in the loop.
// Model: 64 RL + 256 FMA + 32 b128 + ~44 misc ~= 396 instr ~= 900cy/step.

#define T_LEN 1024
#define BATCH 512
#define HID   64

__device__ __forceinline__ float fast_rcp(float x) {
    return __builtin_amdgcn_rcpf(x);  // v_rcp_f32, ~1e-7 rel err
}
__device__ __forceinline__ float fast_tanh(float x) {
    // 1 - 2/(e^{2x}+1); saturates correctly for |x| large
    return 1.0f - 2.0f * fast_rcp(__expf(2.0f * x) + 1.0f);
}

#define RL16(DST, OFF)                                                      \
    _Pragma("unroll")                                                       \
    for (int k = 0; k < 16; ++k) DST[k] = __builtin_amdgcn_readlane(hb, (OFF) + k);

// One 16-k batch: 64 FMAs (4 gates). Gates 0,1 from resident w0/w1;
// gates 2,3 from streamed float4 regs WG/WO.
#define FMA_BATCH(BASE, HS, WG, WO)                                         \
    _Pragma("unroll")                                                       \
    for (int j = 0; j < 4; ++j) {                                           \
        const float h0 = __int_as_float(HS[4*j+0]);                         \
        const float h1 = __int_as_float(HS[4*j+1]);                         \
        const float h2 = __int_as_float(HS[4*j+2]);                         \
        const float h3 = __int_as_float(HS[4*j+3]);                         \
        ai = fmaf(w0[(BASE)+4*j+0], h0, ai);                                \
        af = fmaf(w1[(BASE)+4*j+0], h0, af);                                \
        ag = fmaf(WG[j].x, h0, ag);                                         \
        ao = fmaf(WO[j].x, h0, ao);                                         \
        ai = fmaf(w0[(BASE)+4*j+1], h1, ai);                                \
        af = fmaf(w1[(BASE)+4*j+1], h1, af);                                \
        ag = fmaf(WG[j].y, h1, ag);                                         \
        ao = fmaf(WO[j].y, h1, ao);                                         \
        ai = fmaf(w0[(BASE)+4*j+2], h2, ai);                                \
        af = fmaf(w1[(BASE)+4*j+2], h2, af);                                \
        ag = fmaf(WG[j].z, h2, ag);                                         \
        ao = fmaf(WO[j].z, h2, ao);                                         \
        ai = fmaf(w0[(BASE)+4*j+3], h3, ai);                                \
        af = fmaf(w1[(BASE)+4*j+3], h3, af);                                \
        ag = fmaf(WG[j].w, h3, ag);                                         \
        ao = fmaf(WO[j].w, h3, ao);                                         \
    }

// Prefetch weight batch K4 (4 consecutive float4-columns) for gates 2,3.
#define PREFETCH(DSTG, DSTO, K4)                                            \
    _Pragma("unroll")                                                       \
    for (int j = 0; j < 4; ++j) {                                           \
        DSTG[j] = Tg4[((K4) + j) * HID + lane];                             \
        DSTO[j] = To4[((K4) + j) * HID + lane];                             \
    }

__global__ __launch_bounds__(256, 1)
void lstm_seq_kernel(const float* __restrict__ x,
                     const float* __restrict__ W_ih,
                     const float* __restrict__ W_hh,
                     const float* __restrict__ b_ih,
                     const float* __restrict__ b_hh,
                     const float* __restrict__ W_fc,
                     const float* __restrict__ b_fc,
                     float* __restrict__ out,
                     float* __restrict__ hist)   // d_ws: 1024*64 floats
{
    __shared__ float  xs[2 * T_LEN];     // 8 KB: x[:,511,:]
    __shared__ float4 Tg4[16 * HID];     // 16 KB: gate2 (g) weights, transposed [k4][lane]
    __shared__ float4 To4[16 * HID];     // 16 KB: gate3 (o) weights, transposed [k4][lane]

    const int tid  = threadIdx.x;
    const int lane = tid & 63;
    const int wave = tid >> 6;

    // ---- stage x[:,511,:] into LDS (all 4 waves, one-time)
    for (int j = 0; j < 4; ++j) {
        int t = tid + j * 256;              // 0..1023
        const float2 v = *(const float2*)(x + (size_t)(t * BATCH + (BATCH - 1)) * 2);
        xs[2 * t]     = v.x;
        xs[2 * t + 1] = v.y;
    }
    // ---- stage gates 2,3 weights transposed: T[k4][l] = W_hh[g*64+l][4*k4..+3]
    {
        const float4* W4 = (const float4*)W_hh;
        for (int idx = tid; idx < 1024; idx += 256) {
            const int l  = idx >> 4;        // 0..63
            const int k4 = idx & 15;        // 0..15
            Tg4[k4 * HID + l] = W4[(2 * HID + l) * 16 + k4];
            To4[k4 * HID + l] = W4[(3 * HID + l) * 16 + k4];
        }
    }
    __syncthreads();                        // xs + Tg4/To4 visible to wave 0

    if (wave == 0) {
        // ---- gates 0,1 weights resident in VGPRs (128 regs)
        float w0[HID], w1[HID];
        {
            const float4* r0 = (const float4*)(W_hh + (0 * HID + lane) * HID);
            const float4* r1 = (const float4*)(W_hh + (1 * HID + lane) * HID);
            #pragma unroll
            for (int k = 0; k < 16; ++k) {
                float4 a = r0[k];
                w0[4*k+0] = a.x; w0[4*k+1] = a.y; w0[4*k+2] = a.z; w0[4*k+3] = a.w;
                float4 b = r1[k];
                w1[4*k+0] = b.x; w1[4*k+1] = b.y; w1[4*k+2] = b.z; w1[4*k+3] = b.w;
            }
        }
        float wi0[4], wi1[4], bs[4];
        #pragma unroll
        for (int g = 0; g < 4; ++g) {
            const int row = g * HID + lane;
            wi0[g] = W_ih[row * 2 + 0];
            wi1[g] = W_ih[row * 2 + 1];
            bs[g]  = b_ih[row] + b_hh[row];
        }

        // ---- double-buffered incoming weight regs for gates 2,3 (64 regs)
        float4 Ag[4], Ao[4], Bg[4], Bo[4];
        PREFETCH(Ag, Ao, 0);                // batch 0 -> A
        PREFETCH(Bg, Bo, 4);                // batch 1 -> B

        float hval = 0.0f;   // lane l holds h[l]
        float cval = 0.0f;   // lane l holds c[l]

        for (int t = 0; t < T_LEN; ++t) {
            const float2 xv = *(const float2*)(xs + 2 * t);   // uniform bcast
            const int hb = __float_as_int(hval);

            // seed accumulators with bias + x-part (issues while RL0 runs)
            float ai = fmaf(wi1[0], xv.y, fmaf(wi0[0], xv.x, bs[0]));
            float af = fmaf(wi1[1], xv.y, fmaf(wi0[1], xv.x, bs[1]));
            float ag = fmaf(wi1[2], xv.y, fmaf(wi0[2], xv.x, bs[2]));
            float ao = fmaf(wi1[3], xv.y, fmaf(wi0[3], xv.x, bs[3]));

            int hsA[16], hsB[16];

            RL16(hsA, 0);                               // h[0..15]
            __builtin_amdgcn_sched_barrier(0);

            FMA_BATCH(0, hsA, Ag, Ao);                  // k=0..15 (A)
            PREFETCH(Ag, Ao, 8);                        // batch 2 -> A (after A consumed)
            RL16(hsB, 16);                              // h[16..31]
            __builtin_amdgcn_sched_barrier(0);

            FMA_BATCH(16, hsB, Bg, Bo);                 // k=16..31 (B)
            PREFETCH(Bg, Bo, 12);                       // batch 3 -> B
            RL16(hsA, 32);                              // h[32..47]
            __builtin_amdgcn_sched_barrier(0);

            FMA_BATCH(32, hsA, Ag, Ao);                 // k=32..47 (A)
            PREFETCH(Ag, Ao, 0);                        // next step batch 0 -> A
            RL16(hsB, 48);                              // h[48..63]
            __builtin_amdgcn_sched_barrier(0);

            FMA_BATCH(48, hsB, Bg, Bo);                 // k=48..63 (B)
            PREFETCH(Bg, Bo, 4);                        // next step batch 1 -> B

            // ---- activations (3 sigmoid + 1 tanh, independent chains)
            const float gi = fast_rcp(1.0f + __expf(-ai));
            const float gf = fast_rcp(1.0f + __expf(-af));
            const float go = fast_rcp(1.0f + __expf(-ao));
            const float gg = fmaf(2.0f, fast_rcp(1.0f + __expf(-2.0f * ag)), -1.0f);

            // ---- lane-local update (no exchange, no barrier)
            cval = fmaf(gf, cval, gi * gg);
            hval = go * fast_tanh(cval);

            // h history: coalesced 256B store; never waited on in-loop
            hist[t * HID + lane] = hval;
        }
    }

    __syncthreads();  // wave0's hist stores drained (vmcnt 0) & visible

    // ---- projection: out[t,o] = b_fc[o] + dot(W_fc[o,:], hist[t,:])
    #pragma unroll
    for (int j = 0; j < 8; ++j) {
        const int idx = tid + j * 256;      // 0..2047, coalesced stores
        const int t   = idx >> 1;
        const int o   = idx & 1;
        const float4* hv4 = (const float4*)(hist + t * HID);
        const float4* wv  = (const float4*)(W_fc + o * HID);
        float p0 = 0.f, p1 = 0.f, p2 = 0.f, p3 = 0.f;
        #pragma unroll
        for (int k = 0; k < HID / 4; ++k) {
            float4 h4 = hv4[k], w4 = wv[k];
            p0 = fmaf(h4.x, w4.x, p0);
            p1 = fmaf(h4.y, w4.y, p1);
            p2 = fmaf(h4.z, w4.z, p2);
            p3 = fmaf(h4.w, w4.w, p3);
        }
        out[idx] = b_fc[o] + ((p0 + p1) + (p2 + p3));
    }
}

extern "C" void kernel_launch(void* const* d_in, const int* in_sizes, int n_in,
                              void* d_out, int out_size, void* d_ws, size_t ws_size,
                              hipStream_t stream) {
    const float* x    = (const float*)d_in[0];
    const float* W_ih = (const float*)d_in[1];
    const float* W_hh = (const float*)d_in[2];
    const float* b_ih = (const float*)d_in[3];
    const float* b_hh = (const float*)d_in[4];
    const float* W_fc = (const float*)d_in[5];
    const float* b_fc = (const float*)d_in[6];
    float* out  = (float*)d_out;
    float* hist = (float*)d_ws;   // needs 1024*64*4 = 256 KB

    lstm_seq_kernel<<<dim3(1), dim3(256), 0, stream>>>(
        x, W_ih, W_hh, b_ih, b_hh, W_fc, b_fc, out, hist);
}